// Round 8
// baseline (223.147 us; speedup 1.0000x reference)
//
#include <hip/hip_runtime.h>
#include <stdint.h>

#define D 256
#define KCODES 1024
#define NROWS 65536

using int4v  = __attribute__((ext_vector_type(4))) int;
using int16v = __attribute__((ext_vector_type(16))) int;
using f32x4v = __attribute__((ext_vector_type(4))) float;

__device__ __forceinline__ float rne_f(float x) { return __builtin_rintf(x); }

__device__ __forceinline__ void gl_lds16(const void* g, void* l) {
  __builtin_amdgcn_global_load_lds(
      (const __attribute__((address_space(1))) void*)g,
      (__attribute__((address_space(3))) void*)l, 16, 0, 0);
}

// 4 balanced radix-256 digits of t (|t| <= ~92), each in [-128,127] after an
// exact borrow re-encode of the +128 boundary. Value identical to the
// rounds-2..7 digit chain => bit-identical m.
__device__ __forceinline__ void dig4(float t, int* d) {
  float f0 = rne_f(t);  float t1 = __fmul_rn(__fsub_rn(t, f0), 256.0f);
  float f1 = rne_f(t1); float t2 = __fmul_rn(__fsub_rn(t1, f1), 256.0f);
  float f2 = rne_f(t2); float t3 = __fmul_rn(__fsub_rn(t2, f2), 256.0f);
  float f3 = rne_f(t3);
  int d0 = (int)f0, d1 = (int)f1, d2 = (int)f2, d3 = (int)f3;
  if (d3 == 128) { d3 = -128; ++d2; }
  if (d2 == 128) { d2 = -128; ++d1; }
  if (d1 == 128) { d1 = -128; ++d0; }
  d[0] = d0; d[1] = d1; d[2] = d2; d[3] = d3;
}

// ---------- numpy-exact pairwise sum of squares over 256 elements ----------
__device__ __forceinline__ float np_block128_sumsq(const float* __restrict__ q) {
  float r[8], v[8];
  *(float4*)(v) = *(const float4*)(q);
  *(float4*)(v + 4) = *(const float4*)(q + 4);
#pragma unroll
  for (int j = 0; j < 8; ++j) r[j] = __fmul_rn(v[j], v[j]);
  for (int i = 8; i < 128; i += 8) {
    *(float4*)(v) = *(const float4*)(q + i);
    *(float4*)(v + 4) = *(const float4*)(q + i + 4);
#pragma unroll
    for (int j = 0; j < 8; ++j) r[j] = __fadd_rn(r[j], __fmul_rn(v[j], v[j]));
  }
  float t01 = __fadd_rn(r[0], r[1]);
  float t23 = __fadd_rn(r[2], r[3]);
  float t45 = __fadd_rn(r[4], r[5]);
  float t67 = __fadd_rn(r[6], r[7]);
  return __fadd_rn(__fadd_rn(t01, t23), __fadd_rn(t45, t67));
}
__device__ __forceinline__ float np_sumsq256(const float* __restrict__ q) {
  return __fadd_rn(np_block128_sumsq(q), np_block128_sumsq(q + 128));
}

// ---- fused prep: srow (blocks 0..1023), c2 (1024..1039), cbdig (1040..1103) ----
// srow/c2 blocks: stage 64 rows coalesced into LDS, then 64 threads do the
// numpy-exact pairwise sum per row (round-1 verified pattern).
__global__ __launch_bounds__(256) void prep_all(const float* __restrict__ z,
                                                const float* __restrict__ cb,
                                                float* __restrict__ c2,
                                                float* __restrict__ srow,
                                                char* __restrict__ cbd) {
  __shared__ float zs[64][260];
  const int bid = blockIdx.x;
  const int tid = threadIdx.x;
  if (bid < 1040) {
    const float* src; float* dst; int r0;
    if (bid < 1024) { r0 = bid * 64; src = z; dst = srow; }
    else            { r0 = (bid - 1024) * 64; src = cb; dst = c2; }
#pragma unroll
    for (int it = 0; it < 16; ++it) {
      int g = tid + it * 256, row = g >> 6, f4 = g & 63;
      *(float4*)(&zs[row][f4 * 4]) = *(const float4*)(src + (size_t)(r0 + row) * D + f4 * 4);
    }
    __syncthreads();
    if (tid < 64) dst[r0 + tid] = np_sumsq256(&zs[tid][0]);
    return;
  }
  // cbdig: codebook -> 4 int8 digit planes, k-major tile layout (unchanged r5-r7):
  // plane p, code-tile nt (32 codes) = 8KB tile [f(0..3)][c16(0..1)][kgrp(0..3)]
  // [code(0..15)][16 i8]; 16B chunk covers k = f*64 + kgrp*16 .. +16.
  int id = (bid - 1040) * 256 + tid;  // 0..16383
  int n = id >> 4, kc = id & 15;
  int f = kc >> 2, kg = kc & 3, nt = n >> 5, c = n & 31;
  const float* src = cb + (size_t)n * D + kc * 16;
  float v[16];
  *(float4*)(v) = *(const float4*)(src);
  *(float4*)(v + 4) = *(const float4*)(src + 4);
  *(float4*)(v + 8) = *(const float4*)(src + 8);
  *(float4*)(v + 12) = *(const float4*)(src + 12);
  int dg[16][4];
#pragma unroll
  for (int e = 0; e < 16; ++e) dig4(v[e] * 65536.0f, dg[e]);  // |c*2^16| <= 64
  size_t base = (size_t)nt * 8192 + f * 2048 + (c >> 4) * 1024 + kg * 256 + (c & 15) * 16;
#pragma unroll
  for (int p = 0; p < 4; ++p) {
    int4v wv;
#pragma unroll
    for (int wi = 0; wi < 4; ++wi)
      wv[wi] = (dg[wi * 4][p] & 255) | ((dg[wi * 4 + 1][p] & 255) << 8) |
               ((dg[wi * 4 + 2][p] & 255) << 16) | (dg[wi * 4 + 3][p] << 24);
    *(int4v*)(cbd + (size_t)p * (KCODES * 256) + base) = wv;
  }
}

// ---------------- main MFMA kernel (int8 32x32x32) ----------------
#define BM 128
#define BN 32
#define NT (KCODES / BN)

#define MFI32(a, b, c) __builtin_amdgcn_mfma_i32_32x32x32_i8((a), (b), (c), 0, 0, 0)

// kf-outer, pair-interleaved: all 4 acc chains stay live; same-acc MFMAs >= 2 apart.
// Integer accumulation => order-independent, value identical to rounds 5-7.
__device__ __forceinline__ void compute_tile(const char* buf, const int4v (&Ad)[4][8],
                                             int laneoff, int16v (&acc)[4]) {
#pragma unroll
  for (int s = 0; s < 4; ++s) { int16v zz = {0}; acc[s] = zz; }
#pragma unroll
  for (int kf = 0; kf < 8; ++kf) {
    const char* pb = buf + (kf >> 1) * 2048 + (kf & 1) * 512 + laneoff;
    int4v B0 = *(const int4v*)(pb);
    int4v B1 = *(const int4v*)(pb + 8192);
    int4v B2 = *(const int4v*)(pb + 16384);
    int4v B3 = *(const int4v*)(pb + 24576);
    acc[1] = MFI32(Ad[0][kf], B1, acc[1]);
    acc[3] = MFI32(Ad[0][kf], B3, acc[3]);
    acc[2] = MFI32(Ad[0][kf], B2, acc[2]);
    acc[1] = MFI32(Ad[1][kf], B0, acc[1]);
    acc[3] = MFI32(Ad[1][kf], B2, acc[3]);
    acc[2] = MFI32(Ad[1][kf], B1, acc[2]);
    acc[0] = MFI32(Ad[0][kf], B0, acc[0]);
    acc[3] = MFI32(Ad[2][kf], B1, acc[3]);
    acc[2] = MFI32(Ad[2][kf], B0, acc[2]);
    acc[3] = MFI32(Ad[3][kf], B0, acc[3]);
  }
}

// exact recombination: hi/lo int32 (|.| < 2^31), fp64 fma/mul exact, single
// fp32 rounding => m bit-identical to rounds 2-7.
__device__ __forceinline__ void finalize_tile(const int16v (&acc)[4], int t,
                                              int w, int l31, int hi,
                                              const float* __restrict__ srow_s,
                                              const float* __restrict__ c2s,
                                              float (&bd)[16], int (&bi)[16]) {
  const int kc = t * BN + l31;
  const float c2v = c2s[kc];
#pragma unroll
  for (int r = 0; r < 16; ++r) {
    int hi32 = acc[0][r] * 256 + acc[1][r];
    int lo32 = acc[2][r] * 256 + acc[3][r];
    double md = fma((double)hi32, 65536.0, (double)lo32) * 0x1p-44;
    float mf = (float)md;
    const int row_l = w * 32 + (r & 3) + ((r >> 2) << 3) + (hi << 2);
    float dist = __fsub_rn(__fadd_rn(srow_s[row_l], c2v), __fmul_rn(2.0f, mf));
    if (dist < bd[r]) { bd[r] = dist; bi[r] = kc; }  // ascending kc => first-min
  }
}

__global__ __launch_bounds__(256, 1) void vq_mfma(
    const float* __restrict__ z, const float* __restrict__ cb,
    const float* __restrict__ c2g, const float* __restrict__ srowg,
    const char* __restrict__ cbd, float* __restrict__ out) {
  __shared__ alignas(16) char bbuf[2][32768];  // all 4 planes of one 32-code tile, x2
  __shared__ float c2s[KCODES];
  __shared__ float srow_s[BM];
  __shared__ int bidx_s[BM];

  const int tid = threadIdx.x;
  const int lane = tid & 63;
  const int w = tid >> 6;        // wave 0..3, owns rows w*32..w*32+31
  const int r0 = blockIdx.x * BM;
  const int l31 = lane & 31, hi = lane >> 5;

  c2s[tid] = c2g[tid];
  c2s[tid + 256] = c2g[tid + 256];
  c2s[tid + 512] = c2g[tid + 512];
  c2s[tid + 768] = c2g[tid + 768];
  if (tid < BM) srow_s[tid] = srowg[r0 + tid];

  // ---- A digits: 4 planes x 8 kfrags (32x32x32 A layout: row=l31, k=kf*32+hi*16+e) ----
  int4v Adig[4][8];
  {
    const float* zr = z + (size_t)(r0 + w * 32 + l31) * D + hi * 16;
#pragma unroll
    for (int kf = 0; kf < 8; ++kf) {
      float v[16];
      *(float4*)(v) = *(const float4*)(zr + kf * 32);
      *(float4*)(v + 4) = *(const float4*)(zr + kf * 32 + 4);
      *(float4*)(v + 8) = *(const float4*)(zr + kf * 32 + 8);
      *(float4*)(v + 12) = *(const float4*)(zr + kf * 32 + 12);
      int dg[16][4];
#pragma unroll
      for (int e = 0; e < 16; ++e) dig4(v[e] * 16.0f, dg[e]);  // |z*16| <= ~92
#pragma unroll
      for (int p = 0; p < 4; ++p) {
        int4v wv;
#pragma unroll
        for (int wi = 0; wi < 4; ++wi)
          wv[wi] = (dg[wi * 4][p] & 255) | ((dg[wi * 4 + 1][p] & 255) << 8) |
                   ((dg[wi * 4 + 2][p] & 255) << 16) | (dg[wi * 4 + 3][p] << 24);
        Adig[p][kf] = wv;
      }
    }
  }

  const char* cbd_b = cbd;
#define STAGE_ALL(ntv, dstbase) do { \
    const char* s_ = cbd_b + (size_t)(ntv) * 8192 + tid * 16; \
    char* d_ = (dstbase) + tid * 16; \
    gl_lds16(s_,          d_);          gl_lds16(s_ + 4096,   d_ + 4096); \
    gl_lds16(s_ + 262144, d_ + 8192);   gl_lds16(s_ + 266240, d_ + 12288); \
    gl_lds16(s_ + 524288, d_ + 16384);  gl_lds16(s_ + 528384, d_ + 20480); \
    gl_lds16(s_ + 786432, d_ + 24576);  gl_lds16(s_ + 790528, d_ + 28672); \
  } while (0)

  // per-lane LDS offset for B frags (32x32 B layout: col=l31, k=kf*32+hi*16+e)
  const int laneoff = ((lane >> 4) & 1) * 1024 + hi * 256 + (lane & 15) * 16;

  float bd[16]; int bi[16];
#pragma unroll
  for (int r = 0; r < 16; ++r) { bd[r] = 3.4e38f; bi[r] = 0x7fffffff; }

  int16v accA[4], accB[4];
  char* b0 = &bbuf[0][0];
  char* b1 = &bbuf[1][0];

  STAGE_ALL(0, b0);
  __syncthreads();

  // tile 0 (even -> b0); stage tile 1 into b1 first (issue-before-compute)
  STAGE_ALL(1, b1);
  compute_tile(b0, Adig, laneoff, accA);
  __syncthreads();

  for (int t = 1; t + 1 < NT; t += 2) {
    STAGE_ALL(t + 1, b0);                         // even tile -> b0
    compute_tile(b1, Adig, laneoff, accB);        // odd tile t
    finalize_tile(accA, t - 1, w, l31, hi, srow_s, c2s, bd, bi);  // hides under MFMAs
    __syncthreads();
    STAGE_ALL(t + 2, b1);                         // odd tile -> b1
    compute_tile(b0, Adig, laneoff, accA);        // even tile t+1
    finalize_tile(accB, t, w, l31, hi, srow_s, c2s, bd, bi);
    __syncthreads();
  }
  // tail: tile 31 (odd -> b1)
  compute_tile(b1, Adig, laneoff, accB);
  finalize_tile(accA, NT - 2, w, l31, hi, srow_s, c2s, bd, bi);
  finalize_tile(accB, NT - 1, w, l31, hi, srow_s, c2s, bd, bi);

  // per-row argmin across the 32 code-lanes (np tie-break: lowest idx)
#pragma unroll
  for (int r = 0; r < 16; ++r) {
#pragma unroll
    for (int m = 1; m < 32; m <<= 1) {
      float od = __shfl_xor(bd[r], m);
      int oi = __shfl_xor(bi[r], m);
      if (od < bd[r] || (od == bd[r] && oi < bi[r])) { bd[r] = od; bi[r] = oi; }
    }
    if (l31 == 0) bidx_s[w * 32 + (r & 3) + ((r >> 2) << 3) + (hi << 2)] = bi[r];
  }
  __syncthreads();

  // epilogue: wave-per-row, lane-contiguous 1KB nontemporal stores
  {
    float* out0 = out;
    float* out1 = out + (size_t)NROWS * D;
#pragma unroll
    for (int rr = 0; rr < 32; ++rr) {
      const int row_l = w * 32 + rr;
      const int grow = r0 + row_l;
      const int kb = bidx_s[row_l];
      f32x4v c4 = *(const f32x4v*)(cb + (size_t)kb * D + lane * 4);
      f32x4v z4 = *(const f32x4v*)(z + (size_t)grow * D + lane * 4);
      f32x4v q;
      q.x = __fadd_rn(z4.x, __fsub_rn(c4.x, z4.x));
      q.y = __fadd_rn(z4.y, __fsub_rn(c4.y, z4.y));
      q.z = __fadd_rn(z4.z, __fsub_rn(c4.z, z4.z));
      q.w = __fadd_rn(z4.w, __fsub_rn(c4.w, z4.w));
      __builtin_nontemporal_store(q, (f32x4v*)(out0 + (size_t)grow * D + lane * 4));
      __builtin_nontemporal_store(c4, (f32x4v*)(out1 + (size_t)grow * D + lane * 4));
    }
  }
}

// ---------------- fallback (exact fp64 dot) if ws is too small ----------------
__global__ void c2_kernel_fb(const float* __restrict__ cb, float* __restrict__ c2) {
  int k = blockIdx.x * blockDim.x + threadIdx.x;
  if (k < KCODES) c2[k] = np_sumsq256(cb + (size_t)k * D);
}

__global__ __launch_bounds__(256) void vq_fallback(const float* __restrict__ z,
                                                   const float* __restrict__ cb,
                                                   const float* __restrict__ c2,
                                                   float* __restrict__ out) {
  __shared__ float zs[64][260];
  __shared__ float cs[64][260];
  __shared__ float srow[64];
  __shared__ int bidx[64];
  const int tid = threadIdx.x;
  const int tx = tid & 15, ty = tid >> 4;
  const int r0 = blockIdx.x * 64;
#pragma unroll
  for (int it = 0; it < 16; ++it) {
    int g = tid + it * 256, row = g >> 6, f4 = g & 63;
    *(float4*)(&zs[row][f4 * 4]) = *(const float4*)(z + (size_t)(r0 + row) * D + f4 * 4);
  }
  __syncthreads();
  if (tid < 64) srow[tid] = np_sumsq256(&zs[tid][0]);
  float bd[4]; int bi[4];
#pragma unroll
  for (int j = 0; j < 4; ++j) { bd[j] = 3.4e38f; bi[j] = 0x7fffffff; }
  for (int t = 0; t < KCODES / 64; ++t) {
    __syncthreads();
#pragma unroll
    for (int it = 0; it < 16; ++it) {
      int g = tid + it * 256, row = g >> 6, f4 = g & 63;
      *(float4*)(&cs[row][f4 * 4]) = *(const float4*)(cb + (size_t)(t * 64 + row) * D + f4 * 4);
    }
    __syncthreads();
    double acc[4][4];
#pragma unroll
    for (int j = 0; j < 4; ++j)
#pragma unroll
      for (int i = 0; i < 4; ++i) acc[j][i] = 0.0;
#pragma unroll 2
    for (int d = 0; d < D; d += 4) {
      float4 a[4], b[4];
#pragma unroll
      for (int j = 0; j < 4; ++j) a[j] = *(const float4*)(&zs[ty + 16 * j][d]);
#pragma unroll
      for (int i = 0; i < 4; ++i) b[i] = *(const float4*)(&cs[tx + 16 * i][d]);
#pragma unroll
      for (int j = 0; j < 4; ++j)
#pragma unroll
        for (int i = 0; i < 4; ++i) {
          acc[j][i] += (double)a[j].x * (double)b[i].x;
          acc[j][i] += (double)a[j].y * (double)b[i].y;
          acc[j][i] += (double)a[j].z * (double)b[i].z;
          acc[j][i] += (double)a[j].w * (double)b[i].w;
        }
    }
#pragma unroll
    for (int j = 0; j < 4; ++j) {
      const float s = srow[ty + 16 * j];
#pragma unroll
      for (int i = 0; i < 4; ++i) {
        const int k = t * 64 + tx + 16 * i;
        const float m = (float)acc[j][i];
        const float dist = __fsub_rn(__fadd_rn(s, c2[k]), __fmul_rn(2.0f, m));
        if (dist < bd[j]) { bd[j] = dist; bi[j] = k; }
      }
    }
  }
  __syncthreads();
  float* red_d = &cs[0][0];
  int* red_i = (int*)&cs[20][0];
#pragma unroll
  for (int j = 0; j < 4; ++j) {
    red_d[(ty + 16 * j) * 16 + tx] = bd[j];
    red_i[(ty + 16 * j) * 16 + tx] = bi[j];
  }
  __syncthreads();
  if (tid < 64) {
    float best = red_d[tid * 16 + 0];
    int bsti = red_i[tid * 16 + 0];
    for (int x = 1; x < 16; ++x) {
      float d2 = red_d[tid * 16 + x]; int i2 = red_i[tid * 16 + x];
      if (d2 < best || (d2 == best && i2 < bsti)) { best = d2; bsti = i2; }
    }
    bidx[tid] = bsti;
  }
  __syncthreads();
  const int wid = tid >> 6, lane = tid & 63;
  float* out0 = out;
  float* out1 = out + (size_t)NROWS * D;
  for (int r = wid; r < 64; r += 4) {
    const int gr = r0 + r;
    const int kb = bidx[r];
    float4 c4 = *(const float4*)(cb + (size_t)kb * D + lane * 4);
    float4 z4 = *(const float4*)(&zs[r][lane * 4]);
    float4 q;
    q.x = __fadd_rn(z4.x, __fsub_rn(c4.x, z4.x));
    q.y = __fadd_rn(z4.y, __fsub_rn(c4.y, z4.y));
    q.z = __fadd_rn(z4.z, __fsub_rn(c4.z, z4.z));
    q.w = __fadd_rn(z4.w, __fsub_rn(c4.w, z4.w));
    *(float4*)(out0 + (size_t)gr * D + lane * 4) = q;
    *(float4*)(out1 + (size_t)gr * D + lane * 4) = c4;
  }
}

extern "C" void kernel_launch(void* const* d_in, const int* in_sizes, int n_in,
                              void* d_out, int out_size, void* d_ws, size_t ws_size,
                              hipStream_t stream) {
  const float* z = (const float*)d_in[0];
  const float* cb = (const float*)d_in[1];
  float* out = (float*)d_out;

  const size_t c2_off = 0;                 // 4 KB
  const size_t srow_off = 4096;            // 256 KB
  const size_t cbd_off = 4096 + 262144;    // 1 MB int8 digit planes
  const size_t need = cbd_off + (size_t)4 * KCODES * 256;

  if (ws_size < need) {  // safety fallback: exact fp64 path
    float* c2 = (float*)d_ws;
    c2_kernel_fb<<<KCODES / 256, 256, 0, stream>>>(cb, c2);
    vq_fallback<<<NROWS / 64, 256, 0, stream>>>(z, cb, c2, out);
    return;
  }

  float* c2 = (float*)((char*)d_ws + c2_off);
  float* srow = (float*)((char*)d_ws + srow_off);
  char* cbd = (char*)d_ws + cbd_off;

  prep_all<<<1104, 256, 0, stream>>>(z, cb, c2, srow, cbd);
  vq_mfma<<<NROWS / BM, 256, 0, stream>>>(z, cb, c2, srow, cbd, out);
}

// Round 9
// 191.197 us; speedup vs baseline: 1.1671x; 1.1671x over previous
//
#include <hip/hip_runtime.h>
#include <stdint.h>

#define D 256
#define KCODES 1024
#define NROWS 65536

using int4v  = __attribute__((ext_vector_type(4))) int;
using int16v = __attribute__((ext_vector_type(16))) int;
using f32x4v = __attribute__((ext_vector_type(4))) float;

__device__ __forceinline__ float rne_f(float x) { return __builtin_rintf(x); }

__device__ __forceinline__ void gl_lds16(const void* g, void* l) {
  __builtin_amdgcn_global_load_lds(
      (const __attribute__((address_space(1))) void*)g,
      (__attribute__((address_space(3))) void*)l, 16, 0, 0);
}

// 4 balanced radix-256 digits of t (|t| <= ~92), each in [-128,127] after an
// exact borrow re-encode of the +128 boundary. Value identical to the
// rounds-2..8 digit chain => bit-identical m.
__device__ __forceinline__ void dig4(float t, int* d) {
  float f0 = rne_f(t);  float t1 = __fmul_rn(__fsub_rn(t, f0), 256.0f);
  float f1 = rne_f(t1); float t2 = __fmul_rn(__fsub_rn(t1, f1), 256.0f);
  float f2 = rne_f(t2); float t3 = __fmul_rn(__fsub_rn(t2, f2), 256.0f);
  float f3 = rne_f(t3);
  int d0 = (int)f0, d1 = (int)f1, d2 = (int)f2, d3 = (int)f3;
  if (d3 == 128) { d3 = -128; ++d2; }
  if (d2 == 128) { d2 = -128; ++d1; }
  if (d1 == 128) { d1 = -128; ++d0; }
  d[0] = d0; d[1] = d1; d[2] = d2; d[3] = d3;
}

// ---------- numpy-exact pairwise sum of squares over 256 elements ----------
__device__ __forceinline__ float np_block128_sumsq(const float* __restrict__ q) {
  float r[8], v[8];
  *(float4*)(v) = *(const float4*)(q);
  *(float4*)(v + 4) = *(const float4*)(q + 4);
#pragma unroll
  for (int j = 0; j < 8; ++j) r[j] = __fmul_rn(v[j], v[j]);
  for (int i = 8; i < 128; i += 8) {
    *(float4*)(v) = *(const float4*)(q + i);
    *(float4*)(v + 4) = *(const float4*)(q + i + 4);
#pragma unroll
    for (int j = 0; j < 8; ++j) r[j] = __fadd_rn(r[j], __fmul_rn(v[j], v[j]));
  }
  float t01 = __fadd_rn(r[0], r[1]);
  float t23 = __fadd_rn(r[2], r[3]);
  float t45 = __fadd_rn(r[4], r[5]);
  float t67 = __fadd_rn(r[6], r[7]);
  return __fadd_rn(__fadd_rn(t01, t23), __fadd_rn(t45, t67));
}
__device__ __forceinline__ float np_sumsq256(const float* __restrict__ q) {
  return __fadd_rn(np_block128_sumsq(q), np_block128_sumsq(q + 128));
}

// ---- fused prep: srow (blocks 0..1023), c2 (1024..1039), cbdig (1040..1103) ----
__global__ __launch_bounds__(256) void prep_all(const float* __restrict__ z,
                                                const float* __restrict__ cb,
                                                float* __restrict__ c2,
                                                float* __restrict__ srow,
                                                char* __restrict__ cbd) {
  __shared__ float zs[64][260];
  const int bid = blockIdx.x;
  const int tid = threadIdx.x;
  if (bid < 1040) {
    const float* src; float* dst; int r0;
    if (bid < 1024) { r0 = bid * 64; src = z; dst = srow; }
    else            { r0 = (bid - 1024) * 64; src = cb; dst = c2; }
#pragma unroll
    for (int it = 0; it < 16; ++it) {
      int g = tid + it * 256, row = g >> 6, f4 = g & 63;
      *(float4*)(&zs[row][f4 * 4]) = *(const float4*)(src + (size_t)(r0 + row) * D + f4 * 4);
    }
    __syncthreads();
    if (tid < 64) dst[r0 + tid] = np_sumsq256(&zs[tid][0]);
    return;
  }
  // cbdig: codebook -> 4 int8 digit planes, k-major tile layout (unchanged r5-r8):
  // plane p, code-tile nt (32 codes) = 8KB tile [f(0..3)][c16(0..1)][kgrp(0..3)]
  // [code(0..15)][16 i8]; 16B chunk covers k = f*64 + kgrp*16 .. +16.
  int id = (bid - 1040) * 256 + tid;  // 0..16383
  int n = id >> 4, kc = id & 15;
  int f = kc >> 2, kg = kc & 3, nt = n >> 5, c = n & 31;
  const float* src = cb + (size_t)n * D + kc * 16;
  float v[16];
  *(float4*)(v) = *(const float4*)(src);
  *(float4*)(v + 4) = *(const float4*)(src + 4);
  *(float4*)(v + 8) = *(const float4*)(src + 8);
  *(float4*)(v + 12) = *(const float4*)(src + 12);
  int dg[16][4];
#pragma unroll
  for (int e = 0; e < 16; ++e) dig4(v[e] * 65536.0f, dg[e]);  // |c*2^16| <= 64
  size_t base = (size_t)nt * 8192 + f * 2048 + (c >> 4) * 1024 + kg * 256 + (c & 15) * 16;
#pragma unroll
  for (int p = 0; p < 4; ++p) {
    int4v wv;
#pragma unroll
    for (int wi = 0; wi < 4; ++wi)
      wv[wi] = (dg[wi * 4][p] & 255) | ((dg[wi * 4 + 1][p] & 255) << 8) |
               ((dg[wi * 4 + 2][p] & 255) << 16) | (dg[wi * 4 + 3][p] << 24);
    *(int4v*)(cbd + (size_t)p * (KCODES * 256) + base) = wv;
  }
}

// ---------------- main MFMA kernel (int8 32x32x32) ----------------
#define BM 128
#define BN 32
#define NT (KCODES / BN)

#define MFI32(a, b, c) __builtin_amdgcn_mfma_i32_32x32x32_i8((a), (b), (c), 0, 0, 0)

// kf-outer, pair-interleaved: all 4 acc chains stay live; same-acc MFMAs >= 2 apart.
// Integer accumulation => order-independent, value identical to rounds 5-8.
__device__ __forceinline__ void compute_tile(const char* buf, const int4v (&Ad)[4][8],
                                             int laneoff, int16v (&acc)[4]) {
#pragma unroll
  for (int s = 0; s < 4; ++s) { int16v zz = {0}; acc[s] = zz; }
#pragma unroll
  for (int kf = 0; kf < 8; ++kf) {
    const char* pb = buf + (kf >> 1) * 2048 + (kf & 1) * 512 + laneoff;
    int4v B0 = *(const int4v*)(pb);
    int4v B1 = *(const int4v*)(pb + 8192);
    int4v B2 = *(const int4v*)(pb + 16384);
    int4v B3 = *(const int4v*)(pb + 24576);
    acc[1] = MFI32(Ad[0][kf], B1, acc[1]);
    acc[3] = MFI32(Ad[0][kf], B3, acc[3]);
    acc[2] = MFI32(Ad[0][kf], B2, acc[2]);
    acc[1] = MFI32(Ad[1][kf], B0, acc[1]);
    acc[3] = MFI32(Ad[1][kf], B2, acc[3]);
    acc[2] = MFI32(Ad[1][kf], B1, acc[2]);
    acc[0] = MFI32(Ad[0][kf], B0, acc[0]);
    acc[3] = MFI32(Ad[2][kf], B1, acc[3]);
    acc[2] = MFI32(Ad[2][kf], B0, acc[2]);
    acc[3] = MFI32(Ad[3][kf], B0, acc[3]);
  }
}

// exact recombination: hi/lo int32 (|.| < 2^31), fp64 fma/mul exact, single
// fp32 rounding => m bit-identical to rounds 2-8.
__device__ __forceinline__ void finalize_tile(const int16v (&acc)[4], int t,
                                              int w, int l31, int hi,
                                              const float* __restrict__ srow_s,
                                              const float* __restrict__ c2s,
                                              float (&bd)[16], int (&bi)[16]) {
  const int kc = t * BN + l31;
  const float c2v = c2s[kc];
#pragma unroll
  for (int r = 0; r < 16; ++r) {
    int hi32 = acc[0][r] * 256 + acc[1][r];
    int lo32 = acc[2][r] * 256 + acc[3][r];
    double md = fma((double)hi32, 65536.0, (double)lo32) * 0x1p-44;
    float mf = (float)md;
    const int row_l = w * 32 + (r & 3) + ((r >> 2) << 3) + (hi << 2);
    float dist = __fsub_rn(__fadd_rn(srow_s[row_l], c2v), __fmul_rn(2.0f, mf));
    if (dist < bd[r]) { bd[r] = dist; bi[r] = kc; }  // ascending kc => first-min
  }
}

__global__ __launch_bounds__(256, 1) void vq_mfma(
    const float* __restrict__ z, const float* __restrict__ cb,
    const float* __restrict__ c2g, const float* __restrict__ srowg,
    const char* __restrict__ cbd, float* __restrict__ out) {
  __shared__ alignas(16) char bbuf[2][32768];  // all 4 planes of one 32-code tile, x2
  __shared__ float c2s[KCODES];
  __shared__ float srow_s[BM];
  __shared__ int bidx_s[BM];

  const int tid = threadIdx.x;
  const int lane = tid & 63;
  const int w = tid >> 6;        // wave 0..3, owns rows w*32..w*32+31
  const int r0 = blockIdx.x * BM;
  const int l31 = lane & 31, hi = lane >> 5;

  c2s[tid] = c2g[tid];
  c2s[tid + 256] = c2g[tid + 256];
  c2s[tid + 512] = c2g[tid + 512];
  c2s[tid + 768] = c2g[tid + 768];
  if (tid < BM) srow_s[tid] = srowg[r0 + tid];

  // ---- A digits: 4 planes x 8 kfrags (32x32x32 A layout: row=l31, k=kf*32+hi*16+e) ----
  int4v Adig[4][8];
  {
    const float* zr = z + (size_t)(r0 + w * 32 + l31) * D + hi * 16;
#pragma unroll
    for (int kf = 0; kf < 8; ++kf) {
      float v[16];
      *(float4*)(v) = *(const float4*)(zr + kf * 32);
      *(float4*)(v + 4) = *(const float4*)(zr + kf * 32 + 4);
      *(float4*)(v + 8) = *(const float4*)(zr + kf * 32 + 8);
      *(float4*)(v + 12) = *(const float4*)(zr + kf * 32 + 12);
      int dg[16][4];
#pragma unroll
      for (int e = 0; e < 16; ++e) dig4(v[e] * 16.0f, dg[e]);  // |z*16| <= ~92
#pragma unroll
      for (int p = 0; p < 4; ++p) {
        int4v wv;
#pragma unroll
        for (int wi = 0; wi < 4; ++wi)
          wv[wi] = (dg[wi * 4][p] & 255) | ((dg[wi * 4 + 1][p] & 255) << 8) |
                   ((dg[wi * 4 + 2][p] & 255) << 16) | (dg[wi * 4 + 3][p] << 24);
        Adig[p][kf] = wv;
      }
    }
  }

  const char* cbd_b = cbd;
#define STAGE_ALL(ntv, dstbase) do { \
    const char* s_ = cbd_b + (size_t)(ntv) * 8192 + tid * 16; \
    char* d_ = (dstbase) + tid * 16; \
    gl_lds16(s_,          d_);          gl_lds16(s_ + 4096,   d_ + 4096); \
    gl_lds16(s_ + 262144, d_ + 8192);   gl_lds16(s_ + 266240, d_ + 12288); \
    gl_lds16(s_ + 524288, d_ + 16384);  gl_lds16(s_ + 528384, d_ + 20480); \
    gl_lds16(s_ + 786432, d_ + 24576);  gl_lds16(s_ + 790528, d_ + 28672); \
  } while (0)

  // per-lane LDS offset for B frags (32x32 B layout: col=l31, k=kf*32+hi*16+e)
  const int laneoff = ((lane >> 4) & 1) * 1024 + hi * 256 + (lane & 15) * 16;

  float bd[16]; int bi[16];
#pragma unroll
  for (int r = 0; r < 16; ++r) { bd[r] = 3.4e38f; bi[r] = 0x7fffffff; }

  int16v acc[4];

  STAGE_ALL(0, &bbuf[0][0]);
  __syncthreads();  // stage(0) complete + c2s/srow_s visible

  for (int nt = 0; nt < NT; ++nt) {
    const char* cur = &bbuf[nt & 1][0];
    if (nt + 1 < NT) STAGE_ALL(nt + 1, &bbuf[(nt + 1) & 1][0]);  // issue-before-compute
    compute_tile(cur, Adig, laneoff, acc);
    finalize_tile(acc, nt, w, l31, hi, srow_s, c2s, bd, bi);
    __syncthreads();  // one barrier per nt: drains stage(nt+1), fences cur readers
  }

  // per-row argmin across the 32 code-lanes (np tie-break: lowest idx)
#pragma unroll
  for (int r = 0; r < 16; ++r) {
#pragma unroll
    for (int m = 1; m < 32; m <<= 1) {
      float od = __shfl_xor(bd[r], m);
      int oi = __shfl_xor(bi[r], m);
      if (od < bd[r] || (od == bd[r] && oi < bi[r])) { bd[r] = od; bi[r] = oi; }
    }
    if (l31 == 0) bidx_s[w * 32 + (r & 3) + ((r >> 2) << 3) + (hi << 2)] = bi[r];
  }
  __syncthreads();

  // epilogue: wave-per-row, lane-contiguous 1KB nontemporal stores
  {
    float* out0 = out;
    float* out1 = out + (size_t)NROWS * D;
#pragma unroll
    for (int rr = 0; rr < 32; ++rr) {
      const int row_l = w * 32 + rr;
      const int grow = r0 + row_l;
      const int kb = bidx_s[row_l];
      f32x4v c4 = *(const f32x4v*)(cb + (size_t)kb * D + lane * 4);
      f32x4v z4 = *(const f32x4v*)(z + (size_t)grow * D + lane * 4);
      f32x4v q;
      q.x = __fadd_rn(z4.x, __fsub_rn(c4.x, z4.x));
      q.y = __fadd_rn(z4.y, __fsub_rn(c4.y, z4.y));
      q.z = __fadd_rn(z4.z, __fsub_rn(c4.z, z4.z));
      q.w = __fadd_rn(z4.w, __fsub_rn(c4.w, z4.w));
      __builtin_nontemporal_store(q, (f32x4v*)(out0 + (size_t)grow * D + lane * 4));
      __builtin_nontemporal_store(c4, (f32x4v*)(out1 + (size_t)grow * D + lane * 4));
    }
  }
}

// ---------------- fallback (exact fp64 dot) if ws is too small ----------------
__global__ void c2_kernel_fb(const float* __restrict__ cb, float* __restrict__ c2) {
  int k = blockIdx.x * blockDim.x + threadIdx.x;
  if (k < KCODES) c2[k] = np_sumsq256(cb + (size_t)k * D);
}

__global__ __launch_bounds__(256) void vq_fallback(const float* __restrict__ z,
                                                   const float* __restrict__ cb,
                                                   const float* __restrict__ c2,
                                                   float* __restrict__ out) {
  __shared__ float zs[64][260];
  __shared__ float cs[64][260];
  __shared__ float srow[64];
  __shared__ int bidx[64];
  const int tid = threadIdx.x;
  const int tx = tid & 15, ty = tid >> 4;
  const int r0 = blockIdx.x * 64;
#pragma unroll
  for (int it = 0; it < 16; ++it) {
    int g = tid + it * 256, row = g >> 6, f4 = g & 63;
    *(float4*)(&zs[row][f4 * 4]) = *(const float4*)(z + (size_t)(r0 + row) * D + f4 * 4);
  }
  __syncthreads();
  if (tid < 64) srow[tid] = np_sumsq256(&zs[tid][0]);
  float bd[4]; int bi[4];
#pragma unroll
  for (int j = 0; j < 4; ++j) { bd[j] = 3.4e38f; bi[j] = 0x7fffffff; }
  for (int t = 0; t < KCODES / 64; ++t) {
    __syncthreads();
#pragma unroll
    for (int it = 0; it < 16; ++it) {
      int g = tid + it * 256, row = g >> 6, f4 = g & 63;
      *(float4*)(&cs[row][f4 * 4]) = *(const float4*)(cb + (size_t)(t * 64 + row) * D + f4 * 4);
    }
    __syncthreads();
    double acc[4][4];
#pragma unroll
    for (int j = 0; j < 4; ++j)
#pragma unroll
      for (int i = 0; i < 4; ++i) acc[j][i] = 0.0;
#pragma unroll 2
    for (int d = 0; d < D; d += 4) {
      float4 a[4], b[4];
#pragma unroll
      for (int j = 0; j < 4; ++j) a[j] = *(const float4*)(&zs[ty + 16 * j][d]);
#pragma unroll
      for (int i = 0; i < 4; ++i) b[i] = *(const float4*)(&cs[tx + 16 * i][d]);
#pragma unroll
      for (int j = 0; j < 4; ++j)
#pragma unroll
        for (int i = 0; i < 4; ++i) {
          acc[j][i] += (double)a[j].x * (double)b[i].x;
          acc[j][i] += (double)a[j].y * (double)b[i].y;
          acc[j][i] += (double)a[j].z * (double)b[i].z;
          acc[j][i] += (double)a[j].w * (double)b[i].w;
        }
    }
#pragma unroll
    for (int j = 0; j < 4; ++j) {
      const float s = srow[ty + 16 * j];
#pragma unroll
      for (int i = 0; i < 4; ++i) {
        const int k = t * 64 + tx + 16 * i;
        const float m = (float)acc[j][i];
        const float dist = __fsub_rn(__fadd_rn(s, c2[k]), __fmul_rn(2.0f, m));
        if (dist < bd[j]) { bd[j] = dist; bi[j] = k; }
      }
    }
  }
  __syncthreads();
  float* red_d = &cs[0][0];
  int* red_i = (int*)&cs[20][0];
#pragma unroll
  for (int j = 0; j < 4; ++j) {
    red_d[(ty + 16 * j) * 16 + tx] = bd[j];
    red_i[(ty + 16 * j) * 16 + tx] = bi[j];
  }
  __syncthreads();
  if (tid < 64) {
    float best = red_d[tid * 16 + 0];
    int bsti = red_i[tid * 16 + 0];
    for (int x = 1; x < 16; ++x) {
      float d2 = red_d[tid * 16 + x]; int i2 = red_i[tid * 16 + x];
      if (d2 < best || (d2 == best && i2 < bsti)) { best = d2; bsti = i2; }
    }
    bidx[tid] = bsti;
  }
  __syncthreads();
  const int wid = tid >> 6, lane = tid & 63;
  float* out0 = out;
  float* out1 = out + (size_t)NROWS * D;
  for (int r = wid; r < 64; r += 4) {
    const int gr = r0 + r;
    const int kb = bidx[r];
    float4 c4 = *(const float4*)(cb + (size_t)kb * D + lane * 4);
    float4 z4 = *(const float4*)(&zs[r][lane * 4]);
    float4 q;
    q.x = __fadd_rn(z4.x, __fsub_rn(c4.x, z4.x));
    q.y = __fadd_rn(z4.y, __fsub_rn(c4.y, z4.y));
    q.z = __fadd_rn(z4.z, __fsub_rn(c4.z, z4.z));
    q.w = __fadd_rn(z4.w, __fsub_rn(c4.w, z4.w));
    *(float4*)(out0 + (size_t)gr * D + lane * 4) = q;
    *(float4*)(out1 + (size_t)gr * D + lane * 4) = c4;
  }
}

extern "C" void kernel_launch(void* const* d_in, const int* in_sizes, int n_in,
                              void* d_out, int out_size, void* d_ws, size_t ws_size,
                              hipStream_t stream) {
  const float* z = (const float*)d_in[0];
  const float* cb = (const float*)d_in[1];
  float* out = (float*)d_out;

  const size_t c2_off = 0;                 // 4 KB
  const size_t srow_off = 4096;            // 256 KB
  const size_t cbd_off = 4096 + 262144;    // 1 MB int8 digit planes
  const size_t need = cbd_off + (size_t)4 * KCODES * 256;

  if (ws_size < need) {  // safety fallback: exact fp64 path
    float* c2 = (float*)d_ws;
    c2_kernel_fb<<<KCODES / 256, 256, 0, stream>>>(cb, c2);
    vq_fallback<<<NROWS / 64, 256, 0, stream>>>(z, cb, c2, out);
    return;
  }

  float* c2 = (float*)((char*)d_ws + c2_off);
  float* srow = (float*)((char*)d_ws + srow_off);
  char* cbd = (char*)d_ws + cbd_off;

  prep_all<<<1104, 256, 0, stream>>>(z, cb, c2, srow, cbd);
  vq_mfma<<<NROWS / BM, 256, 0, stream>>>(z, cb, c2, srow, cbd, out);
}

// Round 10
// 175.892 us; speedup vs baseline: 1.2687x; 1.0870x over previous
//
#include <hip/hip_runtime.h>
#include <stdint.h>

#define D 256
#define KCODES 1024
#define NROWS 65536

using int4v  = __attribute__((ext_vector_type(4))) int;
using f32x4v = __attribute__((ext_vector_type(4))) float;

__device__ __forceinline__ float rne_f(float x) { return __builtin_rintf(x); }

__device__ __forceinline__ void gl_lds16(const void* g, void* l) {
  __builtin_amdgcn_global_load_lds(
      (const __attribute__((address_space(1))) void*)g,
      (__attribute__((address_space(3))) void*)l, 16, 0, 0);
}

// 4 balanced radix-256 digits of t (|t| <= ~92), each in [-128,127] after an
// exact borrow re-encode of the +128 boundary. Value identical to the
// rounds-2..9 digit chain => bit-identical m.
__device__ __forceinline__ void dig4(float t, int* d) {
  float f0 = rne_f(t);  float t1 = __fmul_rn(__fsub_rn(t, f0), 256.0f);
  float f1 = rne_f(t1); float t2 = __fmul_rn(__fsub_rn(t1, f1), 256.0f);
  float f2 = rne_f(t2); float t3 = __fmul_rn(__fsub_rn(t2, f2), 256.0f);
  float f3 = rne_f(t3);
  int d0 = (int)f0, d1 = (int)f1, d2 = (int)f2, d3 = (int)f3;
  if (d3 == 128) { d3 = -128; ++d2; }
  if (d2 == 128) { d2 = -128; ++d1; }
  if (d1 == 128) { d1 = -128; ++d0; }
  d[0] = d0; d[1] = d1; d[2] = d2; d[3] = d3;
}

// ---------- numpy-exact pairwise sum of squares over 256 elements ----------
__device__ __forceinline__ float np_block128_sumsq(const float* __restrict__ q) {
  float r[8], v[8];
  *(float4*)(v) = *(const float4*)(q);
  *(float4*)(v + 4) = *(const float4*)(q + 4);
#pragma unroll
  for (int j = 0; j < 8; ++j) r[j] = __fmul_rn(v[j], v[j]);
  for (int i = 8; i < 128; i += 8) {
    *(float4*)(v) = *(const float4*)(q + i);
    *(float4*)(v + 4) = *(const float4*)(q + i + 4);
#pragma unroll
    for (int j = 0; j < 8; ++j) r[j] = __fadd_rn(r[j], __fmul_rn(v[j], v[j]));
  }
  float t01 = __fadd_rn(r[0], r[1]);
  float t23 = __fadd_rn(r[2], r[3]);
  float t45 = __fadd_rn(r[4], r[5]);
  float t67 = __fadd_rn(r[6], r[7]);
  return __fadd_rn(__fadd_rn(t01, t23), __fadd_rn(t45, t67));
}
__device__ __forceinline__ float np_sumsq256(const float* __restrict__ q) {
  return __fadd_rn(np_block128_sumsq(q), np_block128_sumsq(q + 128));
}

// ---- fused prep: srow (blocks 0..1023), c2 (1024..1039), cbdig (1040..1103) ----
__global__ __launch_bounds__(256) void prep_all(const float* __restrict__ z,
                                                const float* __restrict__ cb,
                                                float* __restrict__ c2,
                                                float* __restrict__ srow,
                                                char* __restrict__ cbd) {
  __shared__ float zs[64][260];
  const int bid = blockIdx.x;
  const int tid = threadIdx.x;
  if (bid < 1040) {
    const float* src; float* dst; int r0;
    if (bid < 1024) { r0 = bid * 64; src = z; dst = srow; }
    else            { r0 = (bid - 1024) * 64; src = cb; dst = c2; }
#pragma unroll
    for (int it = 0; it < 16; ++it) {
      int g = tid + it * 256, row = g >> 6, f4 = g & 63;
      *(float4*)(&zs[row][f4 * 4]) = *(const float4*)(src + (size_t)(r0 + row) * D + f4 * 4);
    }
    __syncthreads();
    if (tid < 64) dst[r0 + tid] = np_sumsq256(&zs[tid][0]);
    return;
  }
  // cbdig: codebook -> 4 int8 digit planes, k-major layout (unchanged r5-r9):
  // plane p: [nt32(0..31)][f(0..3)][c16(0..1)][kgrp(0..3)][code(0..15)][16 i8];
  // the 16B chunk covers k = f*64 + kgrp*16 .. +16 of code nt32*32 + c16*16 + code.
  int id = (bid - 1040) * 256 + tid;  // 0..16383
  int n = id >> 4, kc = id & 15;
  int f = kc >> 2, kg = kc & 3, nt = n >> 5, c = n & 31;
  const float* src = cb + (size_t)n * D + kc * 16;
  float v[16];
  *(float4*)(v) = *(const float4*)(src);
  *(float4*)(v + 4) = *(const float4*)(src + 4);
  *(float4*)(v + 8) = *(const float4*)(src + 8);
  *(float4*)(v + 12) = *(const float4*)(src + 12);
  int dg[16][4];
#pragma unroll
  for (int e = 0; e < 16; ++e) dig4(v[e] * 65536.0f, dg[e]);  // |c*2^16| <= 64
  size_t base = (size_t)nt * 8192 + f * 2048 + (c >> 4) * 1024 + kg * 256 + (c & 15) * 16;
#pragma unroll
  for (int p = 0; p < 4; ++p) {
    int4v wv;
#pragma unroll
    for (int wi = 0; wi < 4; ++wi)
      wv[wi] = (dg[wi * 4][p] & 255) | ((dg[wi * 4 + 1][p] & 255) << 8) |
               ((dg[wi * 4 + 2][p] & 255) << 16) | (dg[wi * 4 + 3][p] << 24);
    *(int4v*)(cbd + (size_t)p * (KCODES * 256) + base) = wv;
  }
}

// ---------------- main MFMA kernel (int8 16x16x64, occupancy-first) ----------------
#define BM 64
#define BN 16
#define NT (KCODES / BN)   // 64 tiles of 16 codes

#define MFI16(a, b, c) __builtin_amdgcn_mfma_i32_16x16x64_i8((a), (b), (c), 0, 0, 0)

// (256,4): cap VGPR at 128 -> 4 waves/SIMD; LDS ~37KB -> 4 blocks/CU; 16 waves/CU.
__global__ __launch_bounds__(256, 4) void vq_mfma(
    const float* __restrict__ z, const float* __restrict__ cb,
    const float* __restrict__ c2g, const float* __restrict__ srowg,
    const char* __restrict__ cbd, float* __restrict__ out) {
  __shared__ alignas(16) char bbuf[2][16384];  // 4 planes x 16 codes x 256k, dbuf
  __shared__ float c2s[KCODES];
  __shared__ int bidx_s[BM];

  const int tid = threadIdx.x;
  const int lane = tid & 63;
  const int w = tid >> 6;  // wave 0..3, owns rows w*16..w*16+15
  const int r0 = blockIdx.x * BM;
  const int l15 = lane & 15, l4 = lane >> 4;

  c2s[tid] = c2g[tid];
  c2s[tid + 256] = c2g[tid + 256];
  c2s[tid + 512] = c2g[tid + 512];
  c2s[tid + 768] = c2g[tid + 768];

  float sr[4];
#pragma unroll
  for (int r = 0; r < 4; ++r) sr[r] = srowg[r0 + w * 16 + l4 * 4 + r];

  // ---- A digits: 4 planes x 4 kfrags (16x16x64 A layout: row=l15, k=kf*64+l4*16+e)
  // 64 VGPRs total; digit chain identical to r6 (verified bit-exact).
  int4v Adig[4][4];
  {
    const float* zr = z + (size_t)(r0 + w * 16 + l15) * D + l4 * 16;
#pragma unroll
    for (int f = 0; f < 4; ++f) {
      float v[16];
      *(float4*)(v) = *(const float4*)(zr + f * 64);
      *(float4*)(v + 4) = *(const float4*)(zr + f * 64 + 4);
      *(float4*)(v + 8) = *(const float4*)(zr + f * 64 + 8);
      *(float4*)(v + 12) = *(const float4*)(zr + f * 64 + 12);
      int dg[16][4];
#pragma unroll
      for (int e = 0; e < 16; ++e) dig4(v[e] * 16.0f, dg[e]);  // |z*16| <= ~92
#pragma unroll
      for (int p = 0; p < 4; ++p) {
        int4v wv;
#pragma unroll
        for (int wi = 0; wi < 4; ++wi)
          wv[wi] = (dg[wi * 4][p] & 255) | ((dg[wi * 4 + 1][p] & 255) << 8) |
                   ((dg[wi * 4 + 2][p] & 255) << 16) | (dg[wi * 4 + 3][p] << 24);
        Adig[p][f] = wv;
      }
    }
  }

  const char* cbd_b = cbd;
  // stage the 16-code tile ntv (4 planes x 4KB): wave w stages kf-chunk f=w;
  // each wave's src/dst are linear in lane (gl_lds16 wave-uniform-base rule).
#define STAGE(ntv, dstbase) do { \
    const char* s_ = cbd_b + (size_t)((ntv) >> 1) * 8192 + (tid >> 6) * 2048 + \
                     ((ntv) & 1) * 1024 + (tid & 63) * 16; \
    char* d_ = (dstbase) + (tid >> 6) * 1024 + (tid & 63) * 16; \
    gl_lds16(s_,          d_); \
    gl_lds16(s_ + 262144, d_ + 4096); \
    gl_lds16(s_ + 524288, d_ + 8192); \
    gl_lds16(s_ + 786432, d_ + 12288); \
  } while (0)

  float bd[4]; int bi[4];
#pragma unroll
  for (int r = 0; r < 4; ++r) { bd[r] = 3.4e38f; bi[r] = 0x7fffffff; }

  int4v acc[4];

  STAGE(0, &bbuf[0][0]);
  __syncthreads();  // stage(0) complete + c2s visible

  for (int nt = 0; nt < NT; ++nt) {
    const char* cur = &bbuf[nt & 1][0];
    if (nt + 1 < NT) STAGE(nt + 1, &bbuf[(nt + 1) & 1][0]);  // issue-before-compute
#pragma unroll
    for (int s = 0; s < 4; ++s) { int4v zz = {0, 0, 0, 0}; acc[s] = zz; }
    // 16 ds_reads + 40 MFMAs per wave per tile; acc[j] = sum_{p+q=j} Ad[p]*B[q]
#pragma unroll
    for (int kf = 0; kf < 4; ++kf) {
      const char* pb = cur + kf * 1024 + lane * 16;  // wave-contiguous 1KB: 0 conflicts
      int4v B0 = *(const int4v*)(pb);
      int4v B1 = *(const int4v*)(pb + 4096);
      int4v B2 = *(const int4v*)(pb + 8192);
      int4v B3 = *(const int4v*)(pb + 12288);
      acc[1] = MFI16(Adig[0][kf], B1, acc[1]);
      acc[3] = MFI16(Adig[0][kf], B3, acc[3]);
      acc[2] = MFI16(Adig[0][kf], B2, acc[2]);
      acc[1] = MFI16(Adig[1][kf], B0, acc[1]);
      acc[3] = MFI16(Adig[1][kf], B2, acc[3]);
      acc[2] = MFI16(Adig[1][kf], B1, acc[2]);
      acc[0] = MFI16(Adig[0][kf], B0, acc[0]);
      acc[3] = MFI16(Adig[2][kf], B1, acc[3]);
      acc[2] = MFI16(Adig[2][kf], B0, acc[2]);
      acc[3] = MFI16(Adig[3][kf], B0, acc[3]);
    }
    // finalize: exact recombination (hi in int32: |hi|<2^29; lo via exact fp64 fma),
    // single fp32 rounding => m bit-identical to rounds 2-9.
    {
      const int kc = nt * BN + l15;
      const float c2v = c2s[kc];
#pragma unroll
      for (int r = 0; r < 4; ++r) {
        int hi32 = acc[0][r] * 256 + acc[1][r];
        double lo_d = fma((double)acc[2][r], 256.0, (double)acc[3][r]);
        double md = fma((double)hi32, 65536.0, lo_d) * 0x1p-44;
        float mf = (float)md;
        float dist = __fsub_rn(__fadd_rn(sr[r], c2v), __fmul_rn(2.0f, mf));
        if (dist < bd[r]) { bd[r] = dist; bi[r] = kc; }  // ascending kc => first-min
      }
    }
    __syncthreads();  // one barrier per tile: drains stage(nt+1), fences cur readers
  }

  // per-row argmin across the 16 code-lanes (np tie-break: lowest idx)
#pragma unroll
  for (int r = 0; r < 4; ++r) {
#pragma unroll
    for (int m = 1; m < 16; m <<= 1) {
      float od = __shfl_xor(bd[r], m);
      int oi = __shfl_xor(bi[r], m);
      if (od < bd[r] || (od == bd[r] && oi < bi[r])) { bd[r] = od; bi[r] = oi; }
    }
    if (l15 == 0) bidx_s[w * 16 + l4 * 4 + r] = bi[r];
  }
  __syncthreads();

  // epilogue: wave-per-row, lane-contiguous 1KB nontemporal stores
  {
    float* out0 = out;
    float* out1 = out + (size_t)NROWS * D;
#pragma unroll
    for (int rr = 0; rr < 16; ++rr) {
      const int row_l = w * 16 + rr;
      const int grow = r0 + row_l;
      const int kb = bidx_s[row_l];
      f32x4v c4 = *(const f32x4v*)(cb + (size_t)kb * D + lane * 4);
      f32x4v z4 = *(const f32x4v*)(z + (size_t)grow * D + lane * 4);
      f32x4v q;
      q.x = __fadd_rn(z4.x, __fsub_rn(c4.x, z4.x));
      q.y = __fadd_rn(z4.y, __fsub_rn(c4.y, z4.y));
      q.z = __fadd_rn(z4.z, __fsub_rn(c4.z, z4.z));
      q.w = __fadd_rn(z4.w, __fsub_rn(c4.w, z4.w));
      __builtin_nontemporal_store(q, (f32x4v*)(out0 + (size_t)grow * D + lane * 4));
      __builtin_nontemporal_store(c4, (f32x4v*)(out1 + (size_t)grow * D + lane * 4));
    }
  }
}

// ---------------- fallback (exact fp64 dot) if ws is too small ----------------
__global__ void c2_kernel_fb(const float* __restrict__ cb, float* __restrict__ c2) {
  int k = blockIdx.x * blockDim.x + threadIdx.x;
  if (k < KCODES) c2[k] = np_sumsq256(cb + (size_t)k * D);
}

__global__ __launch_bounds__(256) void vq_fallback(const float* __restrict__ z,
                                                   const float* __restrict__ cb,
                                                   const float* __restrict__ c2,
                                                   float* __restrict__ out) {
  __shared__ float zs[64][260];
  __shared__ float cs[64][260];
  __shared__ float srow[64];
  __shared__ int bidx[64];
  const int tid = threadIdx.x;
  const int tx = tid & 15, ty = tid >> 4;
  const int r0 = blockIdx.x * 64;
#pragma unroll
  for (int it = 0; it < 16; ++it) {
    int g = tid + it * 256, row = g >> 6, f4 = g & 63;
    *(float4*)(&zs[row][f4 * 4]) = *(const float4*)(z + (size_t)(r0 + row) * D + f4 * 4);
  }
  __syncthreads();
  if (tid < 64) srow[tid] = np_sumsq256(&zs[tid][0]);
  float bd[4]; int bi[4];
#pragma unroll
  for (int j = 0; j < 4; ++j) { bd[j] = 3.4e38f; bi[j] = 0x7fffffff; }
  for (int t = 0; t < KCODES / 64; ++t) {
    __syncthreads();
#pragma unroll
    for (int it = 0; it < 16; ++it) {
      int g = tid + it * 256, row = g >> 6, f4 = g & 63;
      *(float4*)(&cs[row][f4 * 4]) = *(const float4*)(cb + (size_t)(t * 64 + row) * D + f4 * 4);
    }
    __syncthreads();
    double acc[4][4];
#pragma unroll
    for (int j = 0; j < 4; ++j)
#pragma unroll
      for (int i = 0; i < 4; ++i) acc[j][i] = 0.0;
#pragma unroll 2
    for (int d = 0; d < D; d += 4) {
      float4 a[4], b[4];
#pragma unroll
      for (int j = 0; j < 4; ++j) a[j] = *(const float4*)(&zs[ty + 16 * j][d]);
#pragma unroll
      for (int i = 0; i < 4; ++i) b[i] = *(const float4*)(&cs[tx + 16 * i][d]);
#pragma unroll
      for (int j = 0; j < 4; ++j)
#pragma unroll
        for (int i = 0; i < 4; ++i) {
          acc[j][i] += (double)a[j].x * (double)b[i].x;
          acc[j][i] += (double)a[j].y * (double)b[i].y;
          acc[j][i] += (double)a[j].z * (double)b[i].z;
          acc[j][i] += (double)a[j].w * (double)b[i].w;
        }
    }
#pragma unroll
    for (int j = 0; j < 4; ++j) {
      const float s = srow[ty + 16 * j];
#pragma unroll
      for (int i = 0; i < 4; ++i) {
        const int k = t * 64 + tx + 16 * i;
        const float m = (float)acc[j][i];
        const float dist = __fsub_rn(__fadd_rn(s, c2[k]), __fmul_rn(2.0f, m));
        if (dist < bd[j]) { bd[j] = dist; bi[j] = k; }
      }
    }
  }
  __syncthreads();
  float* red_d = &cs[0][0];
  int* red_i = (int*)&cs[20][0];
#pragma unroll
  for (int j = 0; j < 4; ++j) {
    red_d[(ty + 16 * j) * 16 + tx] = bd[j];
    red_i[(ty + 16 * j) * 16 + tx] = bi[j];
  }
  __syncthreads();
  if (tid < 64) {
    float best = red_d[tid * 16 + 0];
    int bsti = red_i[tid * 16 + 0];
    for (int x = 1; x < 16; ++x) {
      float d2 = red_d[tid * 16 + x]; int i2 = red_i[tid * 16 + x];
      if (d2 < best || (d2 == best && i2 < bsti)) { best = d2; bsti = i2; }
    }
    bidx[tid] = bsti;
  }
  __syncthreads();
  const int wid = tid >> 6, lane = tid & 63;
  float* out0 = out;
  float* out1 = out + (size_t)NROWS * D;
  for (int r = wid; r < 64; r += 4) {
    const int gr = r0 + r;
    const int kb = bidx[r];
    float4 c4 = *(const float4*)(cb + (size_t)kb * D + lane * 4);
    float4 z4 = *(const float4*)(&zs[r][lane * 4]);
    float4 q;
    q.x = __fadd_rn(z4.x, __fsub_rn(c4.x, z4.x));
    q.y = __fadd_rn(z4.y, __fsub_rn(c4.y, z4.y));
    q.z = __fadd_rn(z4.z, __fsub_rn(c4.z, z4.z));
    q.w = __fadd_rn(z4.w, __fsub_rn(c4.w, z4.w));
    *(float4*)(out0 + (size_t)gr * D + lane * 4) = q;
    *(float4*)(out1 + (size_t)gr * D + lane * 4) = c4;
  }
}

extern "C" void kernel_launch(void* const* d_in, const int* in_sizes, int n_in,
                              void* d_out, int out_size, void* d_ws, size_t ws_size,
                              hipStream_t stream) {
  const float* z = (const float*)d_in[0];
  const float* cb = (const float*)d_in[1];
  float* out = (float*)d_out;

  const size_t c2_off = 0;                 // 4 KB
  const size_t srow_off = 4096;            // 256 KB
  const size_t cbd_off = 4096 + 262144;    // 1 MB int8 digit planes
  const size_t need = cbd_off + (size_t)4 * KCODES * 256;

  if (ws_size < need) {  // safety fallback: exact fp64 path
    float* c2 = (float*)d_ws;
    c2_kernel_fb<<<KCODES / 256, 256, 0, stream>>>(cb, c2);
    vq_fallback<<<NROWS / 64, 256, 0, stream>>>(z, cb, c2, out);
    return;
  }

  float* c2 = (float*)((char*)d_ws + c2_off);
  float* srow = (float*)((char*)d_ws + srow_off);
  char* cbd = (char*)d_ws + cbd_off;

  prep_all<<<1104, 256, 0, stream>>>(z, cb, c2, srow, cbd);
  vq_mfma<<<NROWS / BM, 256, 0, stream>>>(z, cb, c2, srow, cbd, out);
}